// Round 1
// baseline (157.668 us; speedup 1.0000x reference)
//
#include <hip/hip_runtime.h>

// mean(x1 @ x2^T) = dot(colsum(x1), colsum(x2)) / N^2
// Phase 1: column sums of both inputs (memory-bound, 64 MiB total read).
// Phase 2: 1024-element dot product in float64, one block.

#define N_ROWS 8192
#define D_COLS 1024
#define BLOCKS_PER_INPUT 512
#define ROWS_PER_BLOCK (N_ROWS / BLOCKS_PER_INPUT)  // 16

__global__ __launch_bounds__(256) void colsum_kernel(
    const float* __restrict__ x1, const float* __restrict__ x2,
    float* __restrict__ cs /* [2][D_COLS], pre-zeroed */) {
  const float* x = (blockIdx.y == 0) ? x1 : x2;
  float* out = cs + blockIdx.y * D_COLS;
  const int tid = threadIdx.x;  // 0..255, owns columns [4*tid, 4*tid+4)
  const float4* xr = (const float4*)x +
                     (size_t)blockIdx.x * ROWS_PER_BLOCK * (D_COLS / 4) + tid;
  float4 acc = make_float4(0.f, 0.f, 0.f, 0.f);
#pragma unroll
  for (int r = 0; r < ROWS_PER_BLOCK; ++r) {
    float4 v = xr[(size_t)r * (D_COLS / 4)];
    acc.x += v.x; acc.y += v.y; acc.z += v.z; acc.w += v.w;
  }
  const int d = tid * 4;
  atomicAdd(&out[d + 0], acc.x);
  atomicAdd(&out[d + 1], acc.y);
  atomicAdd(&out[d + 2], acc.z);
  atomicAdd(&out[d + 3], acc.w);
}

__global__ __launch_bounds__(1024) void dot_kernel(
    const float* __restrict__ cs, float* __restrict__ out) {
  __shared__ double wave_sums[16];
  const int d = threadIdx.x;  // 0..1023
  double p = (double)cs[d] * (double)cs[d + D_COLS];
  // wave-64 butterfly reduce
#pragma unroll
  for (int off = 32; off > 0; off >>= 1) p += __shfl_down(p, off, 64);
  const int lane = d & 63, wave = d >> 6;
  if (lane == 0) wave_sums[wave] = p;
  __syncthreads();
  if (d == 0) {
    double s = 0.0;
#pragma unroll
    for (int w = 0; w < 16; ++w) s += wave_sums[w];
    out[0] = (float)(s / ((double)N_ROWS * (double)N_ROWS));
  }
}

extern "C" void kernel_launch(void* const* d_in, const int* in_sizes, int n_in,
                              void* d_out, int out_size, void* d_ws,
                              size_t ws_size, hipStream_t stream) {
  const float* x1 = (const float*)d_in[0];
  const float* x2 = (const float*)d_in[1];
  float* cs = (float*)d_ws;          // 2 * 1024 floats = 8 KiB
  float* out = (float*)d_out;

  hipMemsetAsync(cs, 0, 2 * D_COLS * sizeof(float), stream);
  colsum_kernel<<<dim3(BLOCKS_PER_INPUT, 2), 256, 0, stream>>>(x1, x2, cs);
  dot_kernel<<<1, 1024, 0, stream>>>(cs, out);
}

// Round 2
// 100.913 us; speedup vs baseline: 1.5624x; 1.5624x over previous
//
#include <hip/hip_runtime.h>

// mean(x1 @ x2^T) = dot(colsum(x1), colsum(x2)) / N^2
// Atomic-free 3-phase tree:
//   P1: per-block partial column sums -> d_ws   (the only HBM-heavy phase)
//   P2: reduce partials per column, multiply s1*s2, per-block dot partial
//   P3: sum 32 block dots, scale, write scalar
// R1 lesson: 1M contended fp32 atomics cost ~60us (WRITE_SIZE 16MB); this
// version has zero atomics and is fully deterministic.

#define N_ROWS 8192
#define D_COLS 1024
#define P_BLK 128                 // partial blocks per input
#define RPB (N_ROWS / P_BLK)      // 64 rows per block
#define P2_BLOCKS 32              // phase-2 blocks (32 columns each)

// d_ws layout: [2][P_BLK][D_COLS] float partials (1 MiB), then [P2_BLOCKS] double.

__global__ __launch_bounds__(256) void colsum_partial(
    const float* __restrict__ x1, const float* __restrict__ x2,
    float* __restrict__ part) {
  const float* x = (blockIdx.y == 0) ? x1 : x2;
  const int tid = threadIdx.x;  // owns columns [4*tid, 4*tid+4)
  const float4* xr =
      (const float4*)x + (size_t)blockIdx.x * RPB * (D_COLS / 4) + tid;
  float4 acc = make_float4(0.f, 0.f, 0.f, 0.f);
#pragma unroll 16
  for (int r = 0; r < RPB; ++r) {
    float4 v = xr[(size_t)r * (D_COLS / 4)];
    acc.x += v.x; acc.y += v.y; acc.z += v.z; acc.w += v.w;
  }
  float4* dst =
      (float4*)(part + ((size_t)blockIdx.y * P_BLK + blockIdx.x) * D_COLS) + tid;
  *dst = acc;  // coalesced 4 KiB per block, no atomics
}

__global__ __launch_bounds__(256) void colreduce_dot(
    const float* __restrict__ part, double* __restrict__ bdot) {
  __shared__ double sh1[256], sh2[256];
  const int t = threadIdx.x;
  const int cl = t & 31;        // column within this block's 32-column chunk
  const int g = t >> 5;         // partial-group 0..7
  const int c = blockIdx.x * 32 + cl;
  const float* p1 = part + c;
  const float* p2 = part + (size_t)P_BLK * D_COLS + c;
  double s1 = 0.0, s2 = 0.0;
  for (int p = g; p < P_BLK; p += 8) {
    s1 += (double)p1[(size_t)p * D_COLS];
    s2 += (double)p2[(size_t)p * D_COLS];
  }
  sh1[t] = s1; sh2[t] = s2;
  __syncthreads();
  if (t < 64) {
    double prod = 0.0;
    if (t < 32) {
      double a = 0.0, b = 0.0;
#pragma unroll
      for (int gg = 0; gg < 8; ++gg) {
        a += sh1[gg * 32 + t];
        b += sh2[gg * 32 + t];
      }
      prod = a * b;  // s1[c] * s2[c]
    }
#pragma unroll
    for (int off = 32; off > 0; off >>= 1) prod += __shfl_down(prod, off, 64);
    if (t == 0) bdot[blockIdx.x] = prod;
  }
}

__global__ __launch_bounds__(64) void final_scale(
    const double* __restrict__ bdot, float* __restrict__ out) {
  const int t = threadIdx.x;
  double s = (t < P2_BLOCKS) ? bdot[t] : 0.0;
#pragma unroll
  for (int off = 32; off > 0; off >>= 1) s += __shfl_down(s, off, 64);
  if (t == 0) out[0] = (float)(s / ((double)N_ROWS * (double)N_ROWS));
}

extern "C" void kernel_launch(void* const* d_in, const int* in_sizes, int n_in,
                              void* d_out, int out_size, void* d_ws,
                              size_t ws_size, hipStream_t stream) {
  const float* x1 = (const float*)d_in[0];
  const float* x2 = (const float*)d_in[1];
  float* part = (float*)d_ws;  // 2 * 128 * 1024 floats = 1 MiB
  double* bdot =
      (double*)((char*)d_ws + (size_t)2 * P_BLK * D_COLS * sizeof(float));
  float* out = (float*)d_out;

  colsum_partial<<<dim3(P_BLK, 2), 256, 0, stream>>>(x1, x2, part);
  colreduce_dot<<<P2_BLOCKS, 256, 0, stream>>>(part, bdot);
  final_scale<<<1, 64, 0, stream>>>(bdot, out);
}